// Round 1
// baseline (268.547 us; speedup 1.0000x reference)
//
#include <hip/hip_runtime.h>
#include <math.h>

// Problem constants (fixed by setup_inputs): B=4, L=2048, d=192, n=64, chunk=128
#define TOK      8192   // B*L tokens
#define DIM      192    // d
#define NST      64     // n (state size)
#define PCHUNK   128    // chunk length
#define NCHUNKS  64     // B * (L/PCHUNK)
#define CPB      16     // chunks per batch
#define BATCH    4
#define NG       4      // n-groups in intra kernel
#define NPG      16     // n per group

// ---------------------------------------------------------------------------
// Generic tiled fp32 GEMM: out[M,N] = act( X[M,K] @ W[N,K]^T + bias[N] )
// act 0: none.  act 1: v = softplus(v+bias); out = exp(v * (-exp(A_log[n])))
// Requires M%64==0, N%64==0, K%16==0. ldx/ldo are row strides in elements.
// ---------------------------------------------------------------------------
__global__ __launch_bounds__(256)
void gemm_kernel(const float* __restrict__ X, int ldx,
                 const float* __restrict__ W,
                 const float* __restrict__ bias,
                 const float* __restrict__ A_log,
                 float* __restrict__ out, int ldo,
                 int K, int act)
{
    __shared__ float Xs[16][68];   // +4 pad keeps float4 alignment, breaks conflicts
    __shared__ float Ws[16][68];
    const int tid = threadIdx.x;
    const int m0 = blockIdx.x * 64;
    const int n0 = blockIdx.y * 64;
    const int tx = tid & 15;
    const int ty = tid >> 4;
    const int lm = (tid * 4) >> 4;   // 0..63 row for staging
    const int lk = (tid * 4) & 15;   // 0,4,8,12

    float acc[4][4] = {};
    for (int k0 = 0; k0 < K; k0 += 16) {
        float4 xv = *(const float4*)(X + (size_t)(m0 + lm) * ldx + k0 + lk);
        float4 wv = *(const float4*)(W + (size_t)(n0 + lm) * K   + k0 + lk);
        Xs[lk+0][lm] = xv.x; Xs[lk+1][lm] = xv.y; Xs[lk+2][lm] = xv.z; Xs[lk+3][lm] = xv.w;
        Ws[lk+0][lm] = wv.x; Ws[lk+1][lm] = wv.y; Ws[lk+2][lm] = wv.z; Ws[lk+3][lm] = wv.w;
        __syncthreads();
        #pragma unroll
        for (int k = 0; k < 16; ++k) {
            float4 a = *(const float4*)&Xs[k][ty * 4];
            float4 b = *(const float4*)&Ws[k][tx * 4];
            float av[4] = {a.x, a.y, a.z, a.w};
            float bv[4] = {b.x, b.y, b.z, b.w};
            #pragma unroll
            for (int i = 0; i < 4; ++i)
                #pragma unroll
                for (int j = 0; j < 4; ++j)
                    acc[i][j] = fmaf(av[i], bv[j], acc[i][j]);
        }
        __syncthreads();
    }
    #pragma unroll
    for (int i = 0; i < 4; ++i) {
        int m = m0 + ty * 4 + i;
        #pragma unroll
        for (int j = 0; j < 4; ++j) {
            int nn = n0 + tx * 4 + j;
            float v = acc[i][j];
            if (bias) v += bias[nn];
            if (act == 1) {
                float Av = -expf(A_log[nn]);
                float sp = (v > 20.f) ? v : log1pf(expf(v));   // softplus
                v = expf(sp * Av);                             // A_bar in (0,1]
            }
            out[(size_t)m * ldo + nn] = v;
        }
    }
}

// ---------------------------------------------------------------------------
// chunk_A[bc,dd] = prod_p A_bar[bc*128+p, dd]
// ---------------------------------------------------------------------------
__global__ __launch_bounds__(256)
void chunkA_kernel(const float* __restrict__ Abar, float* __restrict__ chunkA)
{
    int idx = blockIdx.x * 256 + threadIdx.x;      // 0 .. 64*192-1
    if (idx >= NCHUNKS * DIM) return;
    int dd = idx % DIM;
    int bc = idx / DIM;
    float p = 1.f;
    for (int i = 0; i < PCHUNK; ++i)
        p *= Abar[((size_t)bc * PCHUNK + i) * DIM + dd];
    chunkA[idx] = p;
}

// ---------------------------------------------------------------------------
// chunk_states[bc,nn,dd] = sum_p Bm[t,nn] * x_bar[t,dd] * A_bar[t,dd]
// One block per chunk; B staged fully, xA staged in p-tiles of 32.
// ---------------------------------------------------------------------------
__global__ __launch_bounds__(256)
void chunkstate_kernel(const float* __restrict__ proj,  // x_bar at ld 384
                       const float* __restrict__ Abar,
                       const float* __restrict__ Bm,
                       float* __restrict__ cs)
{
    int bc = blockIdx.x;
    int t0 = bc * PCHUNK;
    __shared__ float Bs[PCHUNK][68];    // 34.8 KB
    __shared__ float xAs[32][200];      // 25.6 KB

    for (int idx = threadIdx.x; idx < PCHUNK * NST; idx += 256) {
        int p = idx / NST, nn = idx % NST;
        Bs[p][nn] = Bm[(size_t)(t0 + p) * NST + nn];
    }
    const int tx = threadIdx.x & 15;   // dd group: dd = tx*12 .. +11
    const int ty = threadIdx.x >> 4;   // nn group: nn = ty*4 .. +3
    float acc[4][12] = {};
    for (int pt = 0; pt < PCHUNK; pt += 32) {
        __syncthreads();
        for (int idx = threadIdx.x; idx < 32 * DIM; idx += 256) {
            int p = idx / DIM, dd = idx % DIM;
            int t = t0 + pt + p;
            xAs[p][dd] = proj[(size_t)t * 384 + dd] * Abar[(size_t)t * DIM + dd];
        }
        __syncthreads();
        for (int p = 0; p < 32; ++p) {
            float bb[4], xa[12];
            #pragma unroll
            for (int q = 0; q < 4; ++q)  bb[q] = Bs[pt + p][ty * 4 + q];
            #pragma unroll
            for (int r = 0; r < 12; ++r) xa[r] = xAs[p][tx * 12 + r];
            #pragma unroll
            for (int q = 0; q < 4; ++q)
                #pragma unroll
                for (int r = 0; r < 12; ++r)
                    acc[q][r] = fmaf(bb[q], xa[r], acc[q][r]);
        }
    }
    #pragma unroll
    for (int q = 0; q < 4; ++q)
        #pragma unroll
        for (int r = 0; r < 12; ++r)
            cs[((size_t)bc * NST + ty * 4 + q) * DIM + tx * 12 + r] = acc[q][r];
}

// ---------------------------------------------------------------------------
// Inter-chunk scan over c (16 steps). prev[c] = state BEFORE update.
// One thread per (b,nn,dd) = 49152 threads.
// ---------------------------------------------------------------------------
__global__ __launch_bounds__(256)
void scan_kernel(const float* __restrict__ chunkA,
                 const float* __restrict__ cs,
                 float* __restrict__ prev)
{
    int idx = blockIdx.x * 256 + threadIdx.x;    // 0 .. 4*64*192-1
    if (idx >= BATCH * NST * DIM) return;
    int dd = idx % DIM;
    int nn = (idx / DIM) % NST;
    int b  = idx / (DIM * NST);
    float st = 0.f;
    for (int c = 0; c < CPB; ++c) {
        int bc = b * CPB + c;
        size_t off = ((size_t)bc * NST + nn) * DIM + dd;
        prev[off] = st;
        st = fmaf(st, chunkA[(size_t)bc * DIM + dd], cs[off]);
    }
}

// ---------------------------------------------------------------------------
// Intra-chunk recurrence + inter-chunk output, per n-group partial:
//  H[i,n,d] = (|Abar[i,d]|+1e-8)*H[i-1,n,d] + B[i,n]*x_bar[i,d]
//  p_y[ng,t,d] = sum_{n in group} C[i,n]*(H[i,n,d] + prev[n,d])
// Grid: (64 chunks, 4 n-groups), 192 threads (one per d channel).
// ---------------------------------------------------------------------------
__global__ __launch_bounds__(192)
void intra_kernel(const float* __restrict__ proj,   // x_bar at ld 384
                  const float* __restrict__ Abar,
                  const float* __restrict__ Bm,
                  const float* __restrict__ Cm,
                  const float* __restrict__ prev,
                  float* __restrict__ p_y)
{
    int bc = blockIdx.x;
    int ng = blockIdx.y;
    int dd = threadIdx.x;      // 0..191
    int t0 = bc * PCHUNK;
    __shared__ float Bs[PCHUNK][NPG];   // 8 KB
    __shared__ float Cs[PCHUNK][NPG];   // 8 KB

    for (int idx = threadIdx.x; idx < PCHUNK * NPG; idx += 192) {
        int i = idx / NPG, j = idx % NPG;
        Bs[i][j] = Bm[(size_t)(t0 + i) * NST + ng * NPG + j];
        Cs[i][j] = Cm[(size_t)(t0 + i) * NST + ng * NPG + j];
    }
    float H[NPG], P[NPG];
    #pragma unroll
    for (int j = 0; j < NPG; ++j) {
        H[j] = 0.f;
        P[j] = prev[((size_t)bc * NST + ng * NPG + j) * DIM + dd];
    }
    __syncthreads();

    float a_cur = fabsf(Abar[(size_t)t0 * DIM + dd]) + 1e-8f;
    float x_cur = proj[(size_t)t0 * 384 + dd];
    for (int i = 0; i < PCHUNK; ++i) {
        int t = t0 + i;
        float a_nxt = 0.f, x_nxt = 0.f;
        if (i + 1 < PCHUNK) {                // prefetch next step
            a_nxt = fabsf(Abar[(size_t)(t + 1) * DIM + dd]) + 1e-8f;
            x_nxt = proj[(size_t)(t + 1) * 384 + dd];
        }
        float yacc = 0.f;
        #pragma unroll
        for (int j = 0; j < NPG; ++j) {
            H[j] = fmaf(H[j], a_cur, Bs[i][j] * x_cur);
            yacc = fmaf(Cs[i][j], H[j] + P[j], yacc);
        }
        p_y[((size_t)ng * TOK + t) * DIM + dd] = yacc;
        a_cur = a_nxt; x_cur = x_nxt;
    }
}

// ---------------------------------------------------------------------------
// y_g = (sum_g p_y[g]) * silu(z)
// ---------------------------------------------------------------------------
__global__ __launch_bounds__(256)
void gate_kernel(const float* __restrict__ p_y,
                 const float* __restrict__ proj,
                 float* __restrict__ y_g)
{
    int idx = blockIdx.x * 256 + threadIdx.x;
    if (idx >= TOK * DIM) return;
    int t = idx / DIM, dd = idx % DIM;
    float y = p_y[idx]
            + p_y[idx + (size_t)1 * TOK * DIM]
            + p_y[idx + (size_t)2 * TOK * DIM]
            + p_y[idx + (size_t)3 * TOK * DIM];
    float zv = proj[(size_t)t * 384 + DIM + dd];
    float s  = zv / (1.f + expf(-zv));      // silu
    y_g[idx] = y * s;
}

// ---------------------------------------------------------------------------
extern "C" void kernel_launch(void* const* d_in, const int* in_sizes, int n_in,
                              void* d_out, int out_size, void* d_ws, size_t ws_size,
                              hipStream_t stream)
{
    const float* x     = (const float*)d_in[0];
    const float* A_log = (const float*)d_in[1];
    const float* W_B   = (const float*)d_in[2];
    const float* W_C   = (const float*)d_in[3];
    const float* W_dt  = (const float*)d_in[4];
    const float* b_dt  = (const float*)d_in[5];
    const float* W_xp  = (const float*)d_in[6];
    const float* b_xp  = (const float*)d_in[7];
    const float* W_out = (const float*)d_in[8];
    const float* b_out = (const float*)d_in[9];
    float* out = (float*)d_out;

    // workspace layout (floats)
    float* ws = (float*)d_ws;
    float* proj   = ws;                         // 8192*384  = 3,145,728
    float* Bm     = proj   + (size_t)TOK * 384; //  524,288
    float* Cm     = Bm     + (size_t)TOK * NST;
    float* Abar   = Cm     + (size_t)TOK * NST; // 1,572,864
    float* chunkA = Abar   + (size_t)TOK * DIM; //   12,288
    float* cs     = chunkA + (size_t)NCHUNKS * DIM;      //  786,432
    float* prev   = cs     + (size_t)NCHUNKS * NST * DIM;//  786,432
    float* p_y    = prev   + (size_t)NCHUNKS * NST * DIM;// 6,291,456
    float* y_g    = cs;   // cs+prev dead after intra; exactly TOK*DIM floats

    dim3 blk(256);

    // 1. proj = x @ W_xp^T + b_xp   (x_bar | z)
    gemm_kernel<<<dim3(TOK/64, 384/64), blk, 0, stream>>>(
        x, DIM, W_xp, b_xp, nullptr, proj, 384, DIM, 0);
    // 2. Bm = x_bar @ W_B^T
    gemm_kernel<<<dim3(TOK/64, 1), blk, 0, stream>>>(
        proj, 384, W_B, nullptr, nullptr, Bm, NST, DIM, 0);
    // 3. Cm = x_bar @ W_C^T
    gemm_kernel<<<dim3(TOK/64, 1), blk, 0, stream>>>(
        proj, 384, W_C, nullptr, nullptr, Cm, NST, DIM, 0);
    // 4. Abar = exp(softplus(x_bar @ W_dt^T + b_dt) * A)
    gemm_kernel<<<dim3(TOK/64, DIM/64), blk, 0, stream>>>(
        proj, 384, W_dt, b_dt, A_log, Abar, DIM, DIM, 1);
    // 5. chunk_A
    chunkA_kernel<<<dim3((NCHUNKS*DIM + 255)/256), blk, 0, stream>>>(Abar, chunkA);
    // 6. chunk_states
    chunkstate_kernel<<<dim3(NCHUNKS), blk, 0, stream>>>(proj, Abar, Bm, cs);
    // 7. inter-chunk scan
    scan_kernel<<<dim3((BATCH*NST*DIM + 255)/256), blk, 0, stream>>>(chunkA, cs, prev);
    // 8. intra recurrence + inter output (partials over 4 n-groups)
    intra_kernel<<<dim3(NCHUNKS, NG), dim3(192), 0, stream>>>(
        proj, Abar, Bm, Cm, prev, p_y);
    // 9. combine + silu gate
    gate_kernel<<<dim3((TOK*DIM + 255)/256), blk, 0, stream>>>(p_y, proj, y_g);
    // 10. out = y_g @ W_out^T + b_out
    gemm_kernel<<<dim3(TOK/64, DIM/64), blk, 0, stream>>>(
        y_g, DIM, W_out, b_out, nullptr, out, DIM, DIM, 0);
}

// Round 2
// 224.788 us; speedup vs baseline: 1.1947x; 1.1947x over previous
//
#include <hip/hip_runtime.h>
#include <math.h>

// Problem constants: B=4, L=2048, d=192, n=64, chunk=128
#define TOK      8192
#define DIM      192
#define NST      64
#define PCHUNK   128
#define NCHUNKS  64
#define CPB      16
#define BATCH    4
#define NG       4      // n-groups
#define NPG      16     // n per group
#define SUB      32     // sub-chunk length
#define NSUB     4      // sub-chunks per chunk

// ---------------------------------------------------------------------------
// Shared GEMM tile body: out[64,64 tile] = act( X[M,K] @ W[N,K]^T + bias )
// act 0: none.  act 1: v = softplus(v+bias); out = exp(v * (-exp(A_log[n])))
// ---------------------------------------------------------------------------
__device__ __forceinline__
void gemm_tile(const float* __restrict__ X, int ldx,
               const float* __restrict__ W,
               const float* __restrict__ bias,
               const float* __restrict__ A_log,
               float* __restrict__ out, int ldo,
               int K, int act, int m0, int n0)
{
    __shared__ float Xs[16][68];
    __shared__ float Ws[16][68];
    const int tid = threadIdx.x;
    const int tx = tid & 15;
    const int ty = tid >> 4;
    const int lm = (tid * 4) >> 4;   // 0..63
    const int lk = (tid * 4) & 15;   // 0,4,8,12

    float acc[4][4] = {};
    for (int k0 = 0; k0 < K; k0 += 16) {
        float4 xv = *(const float4*)(X + (size_t)(m0 + lm) * ldx + k0 + lk);
        float4 wv = *(const float4*)(W + (size_t)(n0 + lm) * K   + k0 + lk);
        Xs[lk+0][lm] = xv.x; Xs[lk+1][lm] = xv.y; Xs[lk+2][lm] = xv.z; Xs[lk+3][lm] = xv.w;
        Ws[lk+0][lm] = wv.x; Ws[lk+1][lm] = wv.y; Ws[lk+2][lm] = wv.z; Ws[lk+3][lm] = wv.w;
        __syncthreads();
        #pragma unroll
        for (int k = 0; k < 16; ++k) {
            float4 a = *(const float4*)&Xs[k][ty * 4];
            float4 b = *(const float4*)&Ws[k][tx * 4];
            float av[4] = {a.x, a.y, a.z, a.w};
            float bv[4] = {b.x, b.y, b.z, b.w};
            #pragma unroll
            for (int i = 0; i < 4; ++i)
                #pragma unroll
                for (int j = 0; j < 4; ++j)
                    acc[i][j] = fmaf(av[i], bv[j], acc[i][j]);
        }
        __syncthreads();
    }
    #pragma unroll
    for (int i = 0; i < 4; ++i) {
        int m = m0 + ty * 4 + i;
        #pragma unroll
        for (int j = 0; j < 4; ++j) {
            int nn = n0 + tx * 4 + j;
            float v = acc[i][j];
            if (bias) v += bias[nn];
            if (act == 1) {
                float Av = -expf(A_log[nn]);
                float sp = (v > 20.f) ? v : log1pf(expf(v));
                v = expf(sp * Av);
            }
            out[(size_t)m * ldo + nn] = v;
        }
    }
}

__global__ __launch_bounds__(256)
void gemm_kernel(const float* __restrict__ X, int ldx,
                 const float* __restrict__ W,
                 const float* __restrict__ bias,
                 const float* __restrict__ A_log,
                 float* __restrict__ out, int ldo,
                 int K, int act)
{
    gemm_tile(X, ldx, W, bias, A_log, out, ldo, K, act,
              blockIdx.x * 64, blockIdx.y * 64);
}

// Fused B / C projection: blockIdx.y selects W_B or W_C (doubles CU coverage)
__global__ __launch_bounds__(256)
void gemm_bc_kernel(const float* __restrict__ proj,
                    const float* __restrict__ W_B,
                    const float* __restrict__ W_C,
                    float* __restrict__ BC)
{
    const float* W = blockIdx.y ? W_C : W_B;
    float* out = BC + (size_t)blockIdx.y * TOK * NST;
    gemm_tile(proj, 384, W, nullptr, nullptr, out, NST, DIM, 0,
              blockIdx.x * 64, 0);
}

// ---------------------------------------------------------------------------
// chunk_states partials over p-quarters:
//   cs_part[ps,bc,nn,dd] = sum_{p in quarter} B[t,nn]*x_bar[t,dd]*Abar[t,dd]
// ---------------------------------------------------------------------------
__global__ __launch_bounds__(256)
void chunkstate_kernel(const float* __restrict__ proj,
                       const float* __restrict__ Abar,
                       const float* __restrict__ Bm,
                       float* __restrict__ cs_part)
{
    int bc = blockIdx.x, ps = blockIdx.y;
    int t0 = bc * PCHUNK + ps * 32;
    __shared__ float Bs[32][68];
    __shared__ float xAs[32][200];
    for (int idx = threadIdx.x; idx < 32 * NST; idx += 256) {
        int p = idx >> 6, nn = idx & 63;
        Bs[p][nn] = Bm[(size_t)(t0 + p) * NST + nn];
    }
    for (int idx = threadIdx.x; idx < 32 * DIM; idx += 256) {
        int p = idx / DIM, dd = idx % DIM;
        int t = t0 + p;
        xAs[p][dd] = proj[(size_t)t * 384 + dd] * Abar[(size_t)t * DIM + dd];
    }
    __syncthreads();
    const int tx = threadIdx.x & 15;   // dd = tx*12..+11
    const int ty = threadIdx.x >> 4;   // nn = ty*4..+3
    float acc[4][12] = {};
    for (int p = 0; p < 32; ++p) {
        float bb[4], xa[12];
        #pragma unroll
        for (int q = 0; q < 4; ++q)  bb[q] = Bs[p][ty * 4 + q];
        #pragma unroll
        for (int r = 0; r < 12; ++r) xa[r] = xAs[p][tx * 12 + r];
        #pragma unroll
        for (int q = 0; q < 4; ++q)
            #pragma unroll
            for (int r = 0; r < 12; ++r)
                acc[q][r] = fmaf(bb[q], xa[r], acc[q][r]);
    }
    size_t base = ((size_t)ps * NCHUNKS + bc) * NST * DIM;
    #pragma unroll
    for (int q = 0; q < 4; ++q)
        #pragma unroll
        for (int r = 0; r < 12; ++r)
            cs_part[base + (size_t)(ty * 4 + q) * DIM + tx * 12 + r] = acc[q][r];
}

// ---------------------------------------------------------------------------
// Sub-chunk local end-state + decay product:
//   S[bc,s,n,dd] = local H at end of sub-chunk; dprod[bc,s,dd] = prod a
// ---------------------------------------------------------------------------
__global__ __launch_bounds__(192)
void sub_state_kernel(const float* __restrict__ proj,
                      const float* __restrict__ Abar,
                      const float* __restrict__ Bm,
                      float* __restrict__ S,
                      float* __restrict__ dprod)
{
    int bc = blockIdx.x, s = blockIdx.y, g = blockIdx.z;
    int dd = threadIdx.x;
    int t0 = bc * PCHUNK + s * SUB;
    __shared__ float Bs[SUB][NPG];
    for (int idx = threadIdx.x; idx < SUB * NPG; idx += 192) {
        int i = idx / NPG, j = idx % NPG;
        Bs[i][j] = Bm[(size_t)(t0 + i) * NST + g * NPG + j];
    }
    __syncthreads();
    float H[NPG] = {};
    float cp = 1.f;
    float a_cur = fabsf(Abar[(size_t)t0 * DIM + dd]) + 1e-8f;
    float x_cur = proj[(size_t)t0 * 384 + dd];
    for (int i = 0; i < SUB; ++i) {
        float a_nxt = 0.f, x_nxt = 0.f;
        if (i + 1 < SUB) {
            a_nxt = fabsf(Abar[(size_t)(t0 + i + 1) * DIM + dd]) + 1e-8f;
            x_nxt = proj[(size_t)(t0 + i + 1) * 384 + dd];
        }
        cp *= a_cur;
        #pragma unroll
        for (int j = 0; j < NPG; ++j)
            H[j] = fmaf(H[j], a_cur, Bs[i][j] * x_cur);
        a_cur = a_nxt; x_cur = x_nxt;
    }
    size_t base = ((size_t)(bc * NSUB + s) * NST + g * NPG) * DIM + dd;
    #pragma unroll
    for (int j = 0; j < NPG; ++j)
        S[base + (size_t)j * DIM] = H[j];
    if (g == 0) dprod[(size_t)(bc * NSUB + s) * DIM + dd] = cp;
}

// chunkA[bc,dd] = prod of the 4 sub-chunk decay products
__global__ __launch_bounds__(256)
void chunkA_kernel(const float* __restrict__ dprod, float* __restrict__ chunkA)
{
    int idx = blockIdx.x * 256 + threadIdx.x;
    if (idx >= NCHUNKS * DIM) return;
    int dd = idx % DIM, bc = idx / DIM;
    float p = 1.f;
    #pragma unroll
    for (int s = 0; s < NSUB; ++s)
        p *= dprod[(size_t)(bc * NSUB + s) * DIM + dd];
    chunkA[idx] = p;
}

// Inter-chunk scan (16 steps); sums the 4 cs partials on the fly.
__global__ __launch_bounds__(256)
void scan_kernel(const float* __restrict__ chunkA,
                 const float* __restrict__ cs_part,
                 float* __restrict__ prev)
{
    int idx = blockIdx.x * 256 + threadIdx.x;
    if (idx >= BATCH * NST * DIM) return;
    int dd = idx % DIM;
    int nn = (idx / DIM) % NST;
    int b  = idx / (DIM * NST);
    const size_t Q = (size_t)NCHUNKS * NST * DIM;
    float st = 0.f;
    for (int c = 0; c < CPB; ++c) {
        int bc = b * CPB + c;
        size_t off = ((size_t)bc * NST + nn) * DIM + dd;
        prev[off] = st;
        float sum = cs_part[off] + cs_part[off + Q] + cs_part[off + 2*Q] + cs_part[off + 3*Q];
        st = fmaf(st, chunkA[(size_t)bc * DIM + dd], sum);
    }
}

// Intra-chunk scan over the 4 sub-chunks (vectorized over dd by 4)
__global__ __launch_bounds__(256)
void sub_scan_kernel(const float* __restrict__ S,
                     const float* __restrict__ dprod,
                     float* __restrict__ carry)
{
    int v = blockIdx.x * 256 + threadIdx.x;     // over NCHUNKS*NST*48
    if (v >= NCHUNKS * NST * 48) return;
    int dd = (v % 48) * 4;
    int nn = (v / 48) % NST;
    int bc = v / (48 * NST);
    float4 st = {0.f, 0.f, 0.f, 0.f};
    #pragma unroll
    for (int s = 0; s < NSUB; ++s) {
        size_t off = ((size_t)(bc * NSUB + s) * NST + nn) * DIM + dd;
        *(float4*)(carry + off) = st;
        float4 dp = *(const float4*)(dprod + (size_t)(bc * NSUB + s) * DIM + dd);
        float4 Sv = *(const float4*)(S + off);
        st.x = fmaf(st.x, dp.x, Sv.x);
        st.y = fmaf(st.y, dp.y, Sv.y);
        st.z = fmaf(st.z, dp.z, Sv.z);
        st.w = fmaf(st.w, dp.w, Sv.w);
    }
}

// ---------------------------------------------------------------------------
// Intra recurrence within a sub-chunk + carry-in + inter-chunk term:
//   H[i] = a*H[i-1] + B*x ; full = H + cp*carry + prev ; y = sum_n C*full
// Grid: (64 chunks, 4 subs, 4 n-groups), 192 threads (one per d)
// ---------------------------------------------------------------------------
__global__ __launch_bounds__(192)
void intra_kernel(const float* __restrict__ proj,
                  const float* __restrict__ Abar,
                  const float* __restrict__ Bm,
                  const float* __restrict__ Cm,
                  const float* __restrict__ prev,
                  const float* __restrict__ carry,
                  float* __restrict__ p_y)
{
    int bc = blockIdx.x, s = blockIdx.y, g = blockIdx.z;
    int dd = threadIdx.x;
    int t0 = bc * PCHUNK + s * SUB;
    __shared__ float Bs[SUB][NPG];
    __shared__ float Cs[SUB][NPG];
    for (int idx = threadIdx.x; idx < SUB * NPG; idx += 192) {
        int i = idx / NPG, j = idx % NPG;
        Bs[i][j] = Bm[(size_t)(t0 + i) * NST + g * NPG + j];
        Cs[i][j] = Cm[(size_t)(t0 + i) * NST + g * NPG + j];
    }
    float H[NPG], P[NPG], CI[NPG];
    #pragma unroll
    for (int j = 0; j < NPG; ++j) {
        H[j] = 0.f;
        P[j]  = prev[((size_t)bc * NST + g * NPG + j) * DIM + dd];
        CI[j] = carry[((size_t)(bc * NSUB + s) * NST + g * NPG + j) * DIM + dd];
    }
    __syncthreads();

    float cp = 1.f;
    float a_cur = fabsf(Abar[(size_t)t0 * DIM + dd]) + 1e-8f;
    float x_cur = proj[(size_t)t0 * 384 + dd];
    for (int i = 0; i < SUB; ++i) {
        int t = t0 + i;
        float a_nxt = 0.f, x_nxt = 0.f;
        if (i + 1 < SUB) {
            a_nxt = fabsf(Abar[(size_t)(t + 1) * DIM + dd]) + 1e-8f;
            x_nxt = proj[(size_t)(t + 1) * 384 + dd];
        }
        cp *= a_cur;
        float ya[4] = {0.f, 0.f, 0.f, 0.f};
        #pragma unroll
        for (int j = 0; j < NPG; ++j) {
            H[j] = fmaf(H[j], a_cur, Bs[i][j] * x_cur);
            float full = fmaf(cp, CI[j], H[j]) + P[j];
            ya[j & 3] = fmaf(Cs[i][j], full, ya[j & 3]);
        }
        p_y[((size_t)g * TOK + t) * DIM + dd] = (ya[0] + ya[1]) + (ya[2] + ya[3]);
        a_cur = a_nxt; x_cur = x_nxt;
    }
}

// y_g = (sum_g p_y[g]) * silu(z)   — float4 over d
__global__ __launch_bounds__(256)
void gate_kernel(const float* __restrict__ p_y,
                 const float* __restrict__ proj,
                 float* __restrict__ y_g)
{
    int v = blockIdx.x * 256 + threadIdx.x;    // over TOK*48
    if (v >= TOK * 48) return;
    int t = v / 48;
    int dd = (v % 48) * 4;
    const size_t Q = (size_t)TOK * DIM;
    size_t off = (size_t)t * DIM + dd;
    float4 y0 = *(const float4*)(p_y + off);
    float4 y1 = *(const float4*)(p_y + off + Q);
    float4 y2 = *(const float4*)(p_y + off + 2*Q);
    float4 y3 = *(const float4*)(p_y + off + 3*Q);
    float4 z  = *(const float4*)(proj + (size_t)t * 384 + DIM + dd);
    float4 r;
    r.x = (y0.x+y1.x+y2.x+y3.x) * (z.x / (1.f + expf(-z.x)));
    r.y = (y0.y+y1.y+y2.y+y3.y) * (z.y / (1.f + expf(-z.y)));
    r.z = (y0.z+y1.z+y2.z+y3.z) * (z.z / (1.f + expf(-z.z)));
    r.w = (y0.w+y1.w+y2.w+y3.w) * (z.w / (1.f + expf(-z.w)));
    *(float4*)(y_g + off) = r;
}

// ---------------------------------------------------------------------------
extern "C" void kernel_launch(void* const* d_in, const int* in_sizes, int n_in,
                              void* d_out, int out_size, void* d_ws, size_t ws_size,
                              hipStream_t stream)
{
    (void)in_sizes; (void)n_in; (void)out_size; (void)ws_size;
    const float* x     = (const float*)d_in[0];
    const float* A_log = (const float*)d_in[1];
    const float* W_B   = (const float*)d_in[2];
    const float* W_C   = (const float*)d_in[3];
    const float* W_dt  = (const float*)d_in[4];
    const float* b_dt  = (const float*)d_in[5];
    const float* W_xp  = (const float*)d_in[6];
    const float* b_xp  = (const float*)d_in[7];
    const float* W_out = (const float*)d_in[8];
    const float* b_out = (const float*)d_in[9];
    float* out = (float*)d_out;

    // workspace layout (floats); aliased lifetimes noted
    float* ws     = (float*)d_ws;
    float* proj   = ws;                                   // TOK*384
    float* BC     = proj   + (size_t)TOK * 384;           // 2*TOK*NST (Bm|Cm)
    float* Bm     = BC;
    float* Cm     = BC     + (size_t)TOK * NST;
    float* Abar   = BC     + (size_t)2 * TOK * NST;       // TOK*DIM ; reused as y_g
    float* chunkA = Abar   + (size_t)TOK * DIM;           // NCHUNKS*DIM
    float* dprod  = chunkA + (size_t)NCHUNKS * DIM;       // NCHUNKS*NSUB*DIM
    float* prev   = dprod  + (size_t)NCHUNKS * NSUB * DIM;        // NCHUNKS*NST*DIM
    float* csc    = prev   + (size_t)NCHUNKS * NST * DIM;         // 4*NCHUNKS*NST*DIM ; reused as carry
    float* p_y    = csc    + (size_t)4 * NCHUNKS * NST * DIM;     // NG*TOK*DIM ; S aliases start
    float* S      = p_y;      // dead before intra writes p_y
    float* carry  = csc;      // cs_part dead after scan
    float* y_g    = Abar;     // Abar dead after intra

    dim3 blk(256);

    gemm_kernel<<<dim3(TOK/64, 384/64), blk, 0, stream>>>(
        x, DIM, W_xp, b_xp, nullptr, proj, 384, DIM, 0);
    gemm_bc_kernel<<<dim3(TOK/64, 2), blk, 0, stream>>>(proj, W_B, W_C, BC);
    gemm_kernel<<<dim3(TOK/64, DIM/64), blk, 0, stream>>>(
        proj, 384, W_dt, b_dt, A_log, Abar, DIM, DIM, 1);
    chunkstate_kernel<<<dim3(NCHUNKS, NSUB), blk, 0, stream>>>(proj, Abar, Bm, csc);
    sub_state_kernel<<<dim3(NCHUNKS, NSUB, NG), dim3(192), 0, stream>>>(
        proj, Abar, Bm, S, dprod);
    chunkA_kernel<<<dim3((NCHUNKS*DIM + 255)/256), blk, 0, stream>>>(dprod, chunkA);
    scan_kernel<<<dim3((BATCH*NST*DIM + 255)/256), blk, 0, stream>>>(chunkA, csc, prev);
    sub_scan_kernel<<<dim3((NCHUNKS*NST*48 + 255)/256), blk, 0, stream>>>(S, dprod, carry);
    intra_kernel<<<dim3(NCHUNKS, NSUB, NG), dim3(192), 0, stream>>>(
        proj, Abar, Bm, Cm, prev, carry, p_y);
    gate_kernel<<<dim3((TOK*48 + 255)/256), blk, 0, stream>>>(p_y, proj, y_g);
    gemm_kernel<<<dim3(TOK/64, DIM/64), blk, 0, stream>>>(
        y_g, DIM, W_out, b_out, nullptr, out, DIM, DIM, 0);
}

// Round 3
// 200.910 us; speedup vs baseline: 1.3367x; 1.1189x over previous
//
#include <hip/hip_runtime.h>
#include <math.h>

// Problem constants: B=4, L=2048, d=192, n=64, chunk=128
#define TOK      8192
#define DIM      192
#define NST      64
#define PCHUNK   128
#define NCHUNKS  64
#define CPB      16
#define BATCH    4
#define NG       4
#define NPG      16
#define SUB      32
#define NSUB     4

typedef __attribute__((ext_vector_type(8))) short  bf16x8;   // 8 bf16 (4 VGPRs)
typedef __attribute__((ext_vector_type(4))) float  f32x4;

__device__ __forceinline__ unsigned short f2bf(float f) {
    unsigned int u = __float_as_uint(f);
    u += 0x7fff + ((u >> 16) & 1);          // RNE
    return (unsigned short)(u >> 16);
}
__device__ __forceinline__ float bf2f(unsigned short h) {
    return __uint_as_float(((unsigned int)h) << 16);
}

// ---------------------------------------------------------------------------
// Cast x + all weights to bf16 (float4 units, segment-dispatched)
// wbcdtb rows: [W_B(64) | W_C(64) | W_dt(192)] x 192
// ---------------------------------------------------------------------------
__global__ __launch_bounds__(256)
void cast_kernel(const float* __restrict__ x,   const float* __restrict__ Wxp,
                 const float* __restrict__ WB,  const float* __restrict__ WC,
                 const float* __restrict__ Wdt, const float* __restrict__ Wout,
                 unsigned short* __restrict__ xb,     unsigned short* __restrict__ wxpb,
                 unsigned short* __restrict__ wbcdtb, unsigned short* __restrict__ woutb)
{
    int u = blockIdx.x * 256 + threadIdx.x;   // float4 unit index
    const float* src; unsigned short* dst; int idx;
    if      (u < 393216) { src = x;    dst = xb;             idx = u; }
    else if (u < 411648) { src = Wxp;  dst = wxpb;           idx = u - 393216; }
    else if (u < 414720) { src = WB;   dst = wbcdtb;         idx = u - 411648; }
    else if (u < 417792) { src = WC;   dst = wbcdtb + 12288; idx = u - 414720; }
    else if (u < 427008) { src = Wdt;  dst = wbcdtb + 24576; idx = u - 417792; }
    else if (u < 436224) { src = Wout; dst = woutb;          idx = u - 427008; }
    else return;
    float4 v = *(const float4*)(src + (size_t)idx * 4);
    ushort4 r; r.x = f2bf(v.x); r.y = f2bf(v.y); r.z = f2bf(v.z); r.w = f2bf(v.w);
    *(ushort4*)(dst + (size_t)idx * 4) = r;
}

// ---------------------------------------------------------------------------
// MFMA wave-tile body: wave computes 64x64 of X[M,K] @ W[N,K]^T (bf16->fp32)
// A frag: m=lane&15, k=(lane>>4)*8+j ; B frag: n=lane&15, same k (NT pattern)
// C/D: col=lane&15, row=(lane>>4)*4+reg   [verified layout]
// ---------------------------------------------------------------------------
__device__ __forceinline__
void mfma_64x64(const unsigned short* __restrict__ X, int ldx,
                const unsigned short* __restrict__ W, int K,
                int m_wave, int n0, int lr, int kg, f32x4 acc[4][4])
{
    for (int k0 = 0; k0 < K; k0 += 32) {
        bf16x8 af[4], bfr[4];
        #pragma unroll
        for (int mi = 0; mi < 4; ++mi)
            af[mi] = *(const bf16x8*)(X + (size_t)(m_wave + mi*16 + lr) * ldx + k0 + kg*8);
        #pragma unroll
        for (int ni = 0; ni < 4; ++ni)
            bfr[ni] = *(const bf16x8*)(W + (size_t)(n0 + ni*16 + lr) * K + k0 + kg*8);
        #pragma unroll
        for (int mi = 0; mi < 4; ++mi)
            #pragma unroll
            for (int ni = 0; ni < 4; ++ni)
                acc[mi][ni] = __builtin_amdgcn_mfma_f32_16x16x32_bf16(
                                  af[mi], bfr[ni], acc[mi][ni], 0, 0, 0);
    }
}

// proj = x @ W_xp^T + b_xp ; writes fp32 proj AND bf16 projb
__global__ __launch_bounds__(256)
void proj_gemm(const unsigned short* __restrict__ xb,
               const unsigned short* __restrict__ wxpb,
               const float* __restrict__ b_xp,
               float* __restrict__ proj, unsigned short* __restrict__ projb)
{
    const int lane = threadIdx.x & 63, wave = threadIdx.x >> 6;
    const int m_wave = blockIdx.x * 256 + wave * 64;
    const int n0 = blockIdx.y * 64;
    const int lr = lane & 15, kg = lane >> 4;
    f32x4 acc[4][4] = {};
    mfma_64x64(xb, DIM, wxpb, DIM, m_wave, n0, lr, kg, acc);
    #pragma unroll
    for (int ni = 0; ni < 4; ++ni) {
        int col = n0 + ni*16 + lr;
        float bias = b_xp[col];
        #pragma unroll
        for (int mi = 0; mi < 4; ++mi)
            #pragma unroll
            for (int r = 0; r < 4; ++r) {
                int row = m_wave + mi*16 + kg*4 + r;
                float v = acc[mi][ni][r] + bias;
                proj [(size_t)row * 384 + col] = v;
                projb[(size_t)row * 384 + col] = f2bf(v);
            }
    }
}

// Fused B|C|dt GEMM over 320 cols: cols<128 -> BC fp32 [TOK][128];
// cols>=128 -> Abar = exp(softplus(v+b_dt)*(-exp(A_log)))  [TOK][192]
__global__ __launch_bounds__(256)
void bcdt_gemm(const unsigned short* __restrict__ projb,
               const unsigned short* __restrict__ wbcdtb,
               const float* __restrict__ b_dt, const float* __restrict__ A_log,
               float* __restrict__ BC, float* __restrict__ Abar)
{
    const int lane = threadIdx.x & 63, wave = threadIdx.x >> 6;
    const int m_wave = blockIdx.x * 256 + wave * 64;
    const int n0 = blockIdx.y * 64;
    const int lr = lane & 15, kg = lane >> 4;
    f32x4 acc[4][4] = {};
    mfma_64x64(projb, 384, wbcdtb, DIM, m_wave, n0, lr, kg, acc);
    if (n0 < 128) {
        #pragma unroll
        for (int ni = 0; ni < 4; ++ni) {
            int col = n0 + ni*16 + lr;
            #pragma unroll
            for (int mi = 0; mi < 4; ++mi)
                #pragma unroll
                for (int r = 0; r < 4; ++r) {
                    int row = m_wave + mi*16 + kg*4 + r;
                    BC[(size_t)row * 128 + col] = acc[mi][ni][r];
                }
        }
    } else {
        #pragma unroll
        for (int ni = 0; ni < 4; ++ni) {
            int c2 = n0 - 128 + ni*16 + lr;
            float bias = b_dt[c2];
            float Av = -expf(A_log[c2]);
            #pragma unroll
            for (int mi = 0; mi < 4; ++mi)
                #pragma unroll
                for (int r = 0; r < 4; ++r) {
                    int row = m_wave + mi*16 + kg*4 + r;
                    float v = acc[mi][ni][r] + bias;
                    float sp = (v > 20.f) ? v : log1pf(expf(v));
                    Abar[(size_t)row * DIM + c2] = expf(sp * Av);
                }
        }
    }
}

// out = y_g @ W_out^T + b_out  (fp32 out)
__global__ __launch_bounds__(256)
void out_gemm(const unsigned short* __restrict__ ygb,
              const unsigned short* __restrict__ woutb,
              const float* __restrict__ b_out, float* __restrict__ out)
{
    const int lane = threadIdx.x & 63, wave = threadIdx.x >> 6;
    const int m_wave = blockIdx.x * 256 + wave * 64;
    const int n0 = blockIdx.y * 64;
    const int lr = lane & 15, kg = lane >> 4;
    f32x4 acc[4][4] = {};
    mfma_64x64(ygb, DIM, woutb, DIM, m_wave, n0, lr, kg, acc);
    #pragma unroll
    for (int ni = 0; ni < 4; ++ni) {
        int col = n0 + ni*16 + lr;
        float bias = b_out[col];
        #pragma unroll
        for (int mi = 0; mi < 4; ++mi)
            #pragma unroll
            for (int r = 0; r < 4; ++r) {
                int row = m_wave + mi*16 + kg*4 + r;
                out[(size_t)row * DIM + col] = acc[mi][ni][r] + bias;
            }
    }
}

// ---------------------------------------------------------------------------
// chunk_states partials over p-quarters (Bm now strided 128)
// ---------------------------------------------------------------------------
__global__ __launch_bounds__(256)
void chunkstate_kernel(const float* __restrict__ proj,
                       const float* __restrict__ Abar,
                       const float* __restrict__ Bm,
                       float* __restrict__ cs_part)
{
    int bc = blockIdx.x, ps = blockIdx.y;
    int t0 = bc * PCHUNK + ps * 32;
    __shared__ float Bs[32][68];
    __shared__ float xAs[32][200];
    for (int idx = threadIdx.x; idx < 32 * NST; idx += 256) {
        int p = idx >> 6, nn = idx & 63;
        Bs[p][nn] = Bm[(size_t)(t0 + p) * 128 + nn];
    }
    for (int idx = threadIdx.x; idx < 32 * DIM; idx += 256) {
        int p = idx / DIM, dd = idx % DIM;
        int t = t0 + p;
        xAs[p][dd] = proj[(size_t)t * 384 + dd] * Abar[(size_t)t * DIM + dd];
    }
    __syncthreads();
    const int tx = threadIdx.x & 15;
    const int ty = threadIdx.x >> 4;
    float acc[4][12] = {};
    for (int p = 0; p < 32; ++p) {
        float bb[4], xa[12];
        #pragma unroll
        for (int q = 0; q < 4; ++q)  bb[q] = Bs[p][ty * 4 + q];
        #pragma unroll
        for (int r = 0; r < 12; ++r) xa[r] = xAs[p][tx * 12 + r];
        #pragma unroll
        for (int q = 0; q < 4; ++q)
            #pragma unroll
            for (int r = 0; r < 12; ++r)
                acc[q][r] = fmaf(bb[q], xa[r], acc[q][r]);
    }
    size_t base = ((size_t)ps * NCHUNKS + bc) * NST * DIM;
    #pragma unroll
    for (int q = 0; q < 4; ++q)
        #pragma unroll
        for (int r = 0; r < 12; ++r)
            cs_part[base + (size_t)(ty * 4 + q) * DIM + tx * 12 + r] = acc[q][r];
}

// ---------------------------------------------------------------------------
// Sub-chunk local end-state + decay product
// ---------------------------------------------------------------------------
__global__ __launch_bounds__(192)
void sub_state_kernel(const float* __restrict__ proj,
                      const float* __restrict__ Abar,
                      const float* __restrict__ Bm,
                      float* __restrict__ S,
                      float* __restrict__ dprod)
{
    int bc = blockIdx.x, s = blockIdx.y, g = blockIdx.z;
    int dd = threadIdx.x;
    int t0 = bc * PCHUNK + s * SUB;
    __shared__ float Bs[SUB][NPG];
    for (int idx = threadIdx.x; idx < SUB * NPG; idx += 192) {
        int i = idx / NPG, j = idx % NPG;
        Bs[i][j] = Bm[(size_t)(t0 + i) * 128 + g * NPG + j];
    }
    __syncthreads();
    float H[NPG] = {};
    float cp = 1.f;
    float a_cur = fabsf(Abar[(size_t)t0 * DIM + dd]) + 1e-8f;
    float x_cur = proj[(size_t)t0 * 384 + dd];
    for (int i = 0; i < SUB; ++i) {
        float a_nxt = 0.f, x_nxt = 0.f;
        if (i + 1 < SUB) {
            a_nxt = fabsf(Abar[(size_t)(t0 + i + 1) * DIM + dd]) + 1e-8f;
            x_nxt = proj[(size_t)(t0 + i + 1) * 384 + dd];
        }
        cp *= a_cur;
        #pragma unroll
        for (int j = 0; j < NPG; ++j)
            H[j] = fmaf(H[j], a_cur, Bs[i][j] * x_cur);
        a_cur = a_nxt; x_cur = x_nxt;
    }
    size_t base = ((size_t)(bc * NSUB + s) * NST + g * NPG) * DIM + dd;
    #pragma unroll
    for (int j = 0; j < NPG; ++j)
        S[base + (size_t)j * DIM] = H[j];
    if (g == 0) dprod[(size_t)(bc * NSUB + s) * DIM + dd] = cp;
}

// Inter-chunk scan (16 steps); chunkA computed inline from dprod
__global__ __launch_bounds__(256)
void scan_kernel(const float* __restrict__ dprod,
                 const float* __restrict__ cs_part,
                 float* __restrict__ prev)
{
    int idx = blockIdx.x * 256 + threadIdx.x;
    if (idx >= BATCH * NST * DIM) return;
    int dd = idx % DIM;
    int nn = (idx / DIM) % NST;
    int b  = idx / (DIM * NST);
    const size_t Q = (size_t)NCHUNKS * NST * DIM;
    float st = 0.f;
    for (int c = 0; c < CPB; ++c) {
        int bc = b * CPB + c;
        size_t off = ((size_t)bc * NST + nn) * DIM + dd;
        prev[off] = st;
        float cA = dprod[(size_t)(bc*NSUB+0) * DIM + dd]
                 * dprod[(size_t)(bc*NSUB+1) * DIM + dd]
                 * dprod[(size_t)(bc*NSUB+2) * DIM + dd]
                 * dprod[(size_t)(bc*NSUB+3) * DIM + dd];
        float sum = cs_part[off] + cs_part[off + Q] + cs_part[off + 2*Q] + cs_part[off + 3*Q];
        st = fmaf(st, cA, sum);
    }
}

// Intra-chunk scan over sub-chunks (float4 over dd)
__global__ __launch_bounds__(256)
void sub_scan_kernel(const float* __restrict__ S,
                     const float* __restrict__ dprod,
                     float* __restrict__ carry)
{
    int v = blockIdx.x * 256 + threadIdx.x;
    if (v >= NCHUNKS * NST * 48) return;
    int dd = (v % 48) * 4;
    int nn = (v / 48) % NST;
    int bc = v / (48 * NST);
    float4 st = {0.f, 0.f, 0.f, 0.f};
    #pragma unroll
    for (int s = 0; s < NSUB; ++s) {
        size_t off = ((size_t)(bc * NSUB + s) * NST + nn) * DIM + dd;
        *(float4*)(carry + off) = st;
        float4 dp = *(const float4*)(dprod + (size_t)(bc * NSUB + s) * DIM + dd);
        float4 Sv = *(const float4*)(S + off);
        st.x = fmaf(st.x, dp.x, Sv.x);
        st.y = fmaf(st.y, dp.y, Sv.y);
        st.z = fmaf(st.z, dp.z, Sv.z);
        st.w = fmaf(st.w, dp.w, Sv.w);
    }
}

// ---------------------------------------------------------------------------
// Intra recurrence within a sub-chunk + carry + inter term
// ---------------------------------------------------------------------------
__global__ __launch_bounds__(192)
void intra_kernel(const float* __restrict__ proj,
                  const float* __restrict__ Abar,
                  const float* __restrict__ Bm,
                  const float* __restrict__ Cm,
                  const float* __restrict__ prev,
                  const float* __restrict__ carry,
                  float* __restrict__ p_y)
{
    int bc = blockIdx.x, s = blockIdx.y, g = blockIdx.z;
    int dd = threadIdx.x;
    int t0 = bc * PCHUNK + s * SUB;
    __shared__ float Bs[SUB][NPG];
    __shared__ float Cs[SUB][NPG];
    for (int idx = threadIdx.x; idx < SUB * NPG; idx += 192) {
        int i = idx / NPG, j = idx % NPG;
        Bs[i][j] = Bm[(size_t)(t0 + i) * 128 + g * NPG + j];
        Cs[i][j] = Cm[(size_t)(t0 + i) * 128 + g * NPG + j];
    }
    float H[NPG], P[NPG], CI[NPG];
    #pragma unroll
    for (int j = 0; j < NPG; ++j) {
        H[j] = 0.f;
        P[j]  = prev[((size_t)bc * NST + g * NPG + j) * DIM + dd];
        CI[j] = carry[((size_t)(bc * NSUB + s) * NST + g * NPG + j) * DIM + dd];
    }
    __syncthreads();

    float cp = 1.f;
    float a_cur = fabsf(Abar[(size_t)t0 * DIM + dd]) + 1e-8f;
    float x_cur = proj[(size_t)t0 * 384 + dd];
    for (int i = 0; i < SUB; ++i) {
        int t = t0 + i;
        float a_nxt = 0.f, x_nxt = 0.f;
        if (i + 1 < SUB) {
            a_nxt = fabsf(Abar[(size_t)(t + 1) * DIM + dd]) + 1e-8f;
            x_nxt = proj[(size_t)(t + 1) * 384 + dd];
        }
        cp *= a_cur;
        float ya[4] = {0.f, 0.f, 0.f, 0.f};
        #pragma unroll
        for (int j = 0; j < NPG; ++j) {
            H[j] = fmaf(H[j], a_cur, Bs[i][j] * x_cur);
            float full = fmaf(cp, CI[j], H[j]) + P[j];
            ya[j & 3] = fmaf(Cs[i][j], full, ya[j & 3]);
        }
        p_y[((size_t)g * TOK + t) * DIM + dd] = (ya[0] + ya[1]) + (ya[2] + ya[3]);
        a_cur = a_nxt; x_cur = x_nxt;
    }
}

// y_g = (sum_g p_y[g]) * silu(z)  -> bf16 for out GEMM
__global__ __launch_bounds__(256)
void gate_kernel(const float* __restrict__ p_y,
                 const float* __restrict__ proj,
                 unsigned short* __restrict__ ygb)
{
    int v = blockIdx.x * 256 + threadIdx.x;    // TOK*48
    if (v >= TOK * 48) return;
    int t = v / 48;
    int dd = (v % 48) * 4;
    const size_t Q = (size_t)TOK * DIM;
    size_t off = (size_t)t * DIM + dd;
    float4 y0 = *(const float4*)(p_y + off);
    float4 y1 = *(const float4*)(p_y + off + Q);
    float4 y2 = *(const float4*)(p_y + off + 2*Q);
    float4 y3 = *(const float4*)(p_y + off + 3*Q);
    float4 z  = *(const float4*)(proj + (size_t)t * 384 + DIM + dd);
    ushort4 r;
    r.x = f2bf((y0.x+y1.x+y2.x+y3.x) * (z.x / (1.f + expf(-z.x))));
    r.y = f2bf((y0.y+y1.y+y2.y+y3.y) * (z.y / (1.f + expf(-z.y))));
    r.z = f2bf((y0.z+y1.z+y2.z+y3.z) * (z.z / (1.f + expf(-z.z))));
    r.w = f2bf((y0.w+y1.w+y2.w+y3.w) * (z.w / (1.f + expf(-z.w))));
    *(ushort4*)(ygb + off) = r;
}

// ---------------------------------------------------------------------------
extern "C" void kernel_launch(void* const* d_in, const int* in_sizes, int n_in,
                              void* d_out, int out_size, void* d_ws, size_t ws_size,
                              hipStream_t stream)
{
    (void)in_sizes; (void)n_in; (void)out_size; (void)ws_size;
    const float* x     = (const float*)d_in[0];
    const float* A_log = (const float*)d_in[1];
    const float* W_B   = (const float*)d_in[2];
    const float* W_C   = (const float*)d_in[3];
    const float* W_dt  = (const float*)d_in[4];
    const float* b_dt  = (const float*)d_in[5];
    const float* W_xp  = (const float*)d_in[6];
    const float* b_xp  = (const float*)d_in[7];
    const float* W_out = (const float*)d_in[8];
    const float* b_out = (const float*)d_in[9];
    float* out = (float*)d_out;

    // byte-carved workspace (all segments 256B aligned)
    char* w = (char*)d_ws;
    auto take = [&](size_t bytes) { char* p = w; w += (bytes + 255) & ~(size_t)255; return p; };
    float*          proj   = (float*)         take((size_t)TOK*384*4);
    unsigned short* projb  = (unsigned short*)take((size_t)TOK*384*2);
    unsigned short* xb     = (unsigned short*)take((size_t)TOK*DIM*2);
    unsigned short* wxpb   = (unsigned short*)take((size_t)384*DIM*2);
    unsigned short* wbcdtb = (unsigned short*)take((size_t)320*DIM*2);
    unsigned short* woutb  = (unsigned short*)take((size_t)DIM*DIM*2);
    float*          BC     = (float*)         take((size_t)TOK*128*4);
    float*          Abar   = (float*)         take((size_t)TOK*DIM*4);
    float*          dprod  = (float*)         take((size_t)NCHUNKS*NSUB*DIM*4);
    float*          prev   = (float*)         take((size_t)NCHUNKS*NST*DIM*4);
    float*          csc    = (float*)         take((size_t)4*NCHUNKS*NST*DIM*4);  // cs partials -> carry
    float*          p_y    = (float*)         take((size_t)NG*TOK*DIM*4);         // S aliases start
    unsigned short* ygb    = (unsigned short*)take((size_t)TOK*DIM*2);
    float* S     = p_y;
    float* carry = csc;
    const float* Bm = BC;         // stride 128
    const float* Cm = BC + 64;    // stride 128

    dim3 blk(256);

    cast_kernel<<<dim3((436224 + 255)/256), blk, 0, stream>>>(
        x, W_xp, W_B, W_C, W_dt, W_out, xb, wxpb, wbcdtb, woutb);
    proj_gemm<<<dim3(TOK/256, 384/64), blk, 0, stream>>>(xb, wxpb, b_xp, proj, projb);
    bcdt_gemm<<<dim3(TOK/256, 320/64), blk, 0, stream>>>(projb, wbcdtb, b_dt, A_log, BC, Abar);
    chunkstate_kernel<<<dim3(NCHUNKS, NSUB), blk, 0, stream>>>(proj, Abar, Bm, csc);
    sub_state_kernel<<<dim3(NCHUNKS, NSUB, NG), dim3(192), 0, stream>>>(
        proj, Abar, Bm, S, dprod);
    scan_kernel<<<dim3((BATCH*NST*DIM + 255)/256), blk, 0, stream>>>(dprod, csc, prev);
    sub_scan_kernel<<<dim3((NCHUNKS*NST*48 + 255)/256), blk, 0, stream>>>(S, dprod, carry);
    intra_kernel<<<dim3(NCHUNKS, NSUB, NG), dim3(192), 0, stream>>>(
        proj, Abar, Bm, Cm, prev, carry, p_y);
    gate_kernel<<<dim3((TOK*48 + 255)/256), blk, 0, stream>>>(p_y, proj, ygb);
    out_gemm<<<dim3(TOK/256, DIM/64), blk, 0, stream>>>(ygb, woutb, b_out, out);
}

// Round 4
// 188.250 us; speedup vs baseline: 1.4265x; 1.0672x over previous
//
#include <hip/hip_runtime.h>
#include <math.h>

// Problem constants: B=4, L=2048, d=192, n=64, chunk=128
#define TOK      8192
#define DIM      192
#define NST      64
#define PCHUNK   128
#define NCHUNKS  64
#define CPB      16
#define BATCH    4
#define SUB      32
#define NSUB     4
#define NG2      2      // n-groups (split n=64 into 2x32)
#define NPG2     32     // n per group

typedef __attribute__((ext_vector_type(8))) short  bf16x8;
typedef __attribute__((ext_vector_type(4))) float  f32x4;

__device__ __forceinline__ unsigned short f2bf(float f) {
    unsigned int u = __float_as_uint(f);
    u += 0x7fff + ((u >> 16) & 1);          // RNE
    return (unsigned short)(u >> 16);
}

// ---------------------------------------------------------------------------
// Cast x + all weights to bf16 (float4 units, segment-dispatched)
// wbcdtb rows: [W_B(64) | W_C(64) | W_dt(192)] x 192
// ---------------------------------------------------------------------------
__global__ __launch_bounds__(256)
void cast_kernel(const float* __restrict__ x,   const float* __restrict__ Wxp,
                 const float* __restrict__ WB,  const float* __restrict__ WC,
                 const float* __restrict__ Wdt, const float* __restrict__ Wout,
                 unsigned short* __restrict__ xb,     unsigned short* __restrict__ wxpb,
                 unsigned short* __restrict__ wbcdtb, unsigned short* __restrict__ woutb)
{
    int u = blockIdx.x * 256 + threadIdx.x;
    const float* src; unsigned short* dst; int idx;
    if      (u < 393216) { src = x;    dst = xb;             idx = u; }
    else if (u < 411648) { src = Wxp;  dst = wxpb;           idx = u - 393216; }
    else if (u < 414720) { src = WB;   dst = wbcdtb;         idx = u - 411648; }
    else if (u < 417792) { src = WC;   dst = wbcdtb + 12288; idx = u - 414720; }
    else if (u < 427008) { src = Wdt;  dst = wbcdtb + 24576; idx = u - 417792; }
    else if (u < 436224) { src = Wout; dst = woutb;          idx = u - 427008; }
    else return;
    float4 v = *(const float4*)(src + (size_t)idx * 4);
    ushort4 r; r.x = f2bf(v.x); r.y = f2bf(v.y); r.z = f2bf(v.z); r.w = f2bf(v.w);
    *(ushort4*)(dst + (size_t)idx * 4) = r;
}

// ---------------------------------------------------------------------------
// MFMA wave-tile body: wave computes 64x64 of X[M,K] @ W[N,K]^T (bf16->fp32)
// ---------------------------------------------------------------------------
__device__ __forceinline__
void mfma_64x64(const unsigned short* __restrict__ X, int ldx,
                const unsigned short* __restrict__ W, int K,
                int m_wave, int n0, int lr, int kg, f32x4 acc[4][4])
{
    for (int k0 = 0; k0 < K; k0 += 32) {
        bf16x8 af[4], bfr[4];
        #pragma unroll
        for (int mi = 0; mi < 4; ++mi)
            af[mi] = *(const bf16x8*)(X + (size_t)(m_wave + mi*16 + lr) * ldx + k0 + kg*8);
        #pragma unroll
        for (int ni = 0; ni < 4; ++ni)
            bfr[ni] = *(const bf16x8*)(W + (size_t)(n0 + ni*16 + lr) * K + k0 + kg*8);
        #pragma unroll
        for (int mi = 0; mi < 4; ++mi)
            #pragma unroll
            for (int ni = 0; ni < 4; ++ni)
                acc[mi][ni] = __builtin_amdgcn_mfma_f32_16x16x32_bf16(
                                  af[mi], bfr[ni], acc[mi][ni], 0, 0, 0);
    }
}

// proj = x @ W_xp^T + b_xp ; writes fp32 proj AND bf16 projb
__global__ __launch_bounds__(256)
void proj_gemm(const unsigned short* __restrict__ xb,
               const unsigned short* __restrict__ wxpb,
               const float* __restrict__ b_xp,
               float* __restrict__ proj, unsigned short* __restrict__ projb)
{
    const int lane = threadIdx.x & 63, wave = threadIdx.x >> 6;
    const int m_wave = blockIdx.x * 256 + wave * 64;
    const int n0 = blockIdx.y * 64;
    const int lr = lane & 15, kg = lane >> 4;
    f32x4 acc[4][4] = {};
    mfma_64x64(xb, DIM, wxpb, DIM, m_wave, n0, lr, kg, acc);
    #pragma unroll
    for (int ni = 0; ni < 4; ++ni) {
        int col = n0 + ni*16 + lr;
        float bias = b_xp[col];
        #pragma unroll
        for (int mi = 0; mi < 4; ++mi)
            #pragma unroll
            for (int r = 0; r < 4; ++r) {
                int row = m_wave + mi*16 + kg*4 + r;
                float v = acc[mi][ni][r] + bias;
                proj [(size_t)row * 384 + col] = v;
                projb[(size_t)row * 384 + col] = f2bf(v);
            }
    }
}

// Fused B|C|dt GEMM over 320 cols: cols<128 -> BC fp32 [TOK][128];
// cols>=128 -> Abar = exp(softplus(v+b_dt)*(-exp(A_log)))  [TOK][192]
__global__ __launch_bounds__(256)
void bcdt_gemm(const unsigned short* __restrict__ projb,
               const unsigned short* __restrict__ wbcdtb,
               const float* __restrict__ b_dt, const float* __restrict__ A_log,
               float* __restrict__ BC, float* __restrict__ Abar)
{
    const int lane = threadIdx.x & 63, wave = threadIdx.x >> 6;
    const int m_wave = blockIdx.x * 256 + wave * 64;
    const int n0 = blockIdx.y * 64;
    const int lr = lane & 15, kg = lane >> 4;
    f32x4 acc[4][4] = {};
    mfma_64x64(projb, 384, wbcdtb, DIM, m_wave, n0, lr, kg, acc);
    if (n0 < 128) {
        #pragma unroll
        for (int ni = 0; ni < 4; ++ni) {
            int col = n0 + ni*16 + lr;
            #pragma unroll
            for (int mi = 0; mi < 4; ++mi)
                #pragma unroll
                for (int r = 0; r < 4; ++r) {
                    int row = m_wave + mi*16 + kg*4 + r;
                    BC[(size_t)row * 128 + col] = acc[mi][ni][r];
                }
        }
    } else {
        #pragma unroll
        for (int ni = 0; ni < 4; ++ni) {
            int c2 = n0 - 128 + ni*16 + lr;
            float bias = b_dt[c2];
            float Av = -expf(A_log[c2]);
            #pragma unroll
            for (int mi = 0; mi < 4; ++mi)
                #pragma unroll
                for (int r = 0; r < 4; ++r) {
                    int row = m_wave + mi*16 + kg*4 + r;
                    float v = acc[mi][ni][r] + bias;
                    float sp = (v > 20.f) ? v : log1pf(expf(v));
                    Abar[(size_t)row * DIM + c2] = expf(sp * Av);
                }
        }
    }
}

// out = y_g @ W_out^T + b_out  (fp32 out)
__global__ __launch_bounds__(256)
void out_gemm(const unsigned short* __restrict__ ygb,
              const unsigned short* __restrict__ woutb,
              const float* __restrict__ b_out, float* __restrict__ out)
{
    const int lane = threadIdx.x & 63, wave = threadIdx.x >> 6;
    const int m_wave = blockIdx.x * 256 + wave * 64;
    const int n0 = blockIdx.y * 64;
    const int lr = lane & 15, kg = lane >> 4;
    f32x4 acc[4][4] = {};
    mfma_64x64(ygb, DIM, woutb, DIM, m_wave, n0, lr, kg, acc);
    #pragma unroll
    for (int ni = 0; ni < 4; ++ni) {
        int col = n0 + ni*16 + lr;
        float bias = b_out[col];
        #pragma unroll
        for (int mi = 0; mi < 4; ++mi)
            #pragma unroll
            for (int r = 0; r < 4; ++r) {
                int row = m_wave + mi*16 + kg*4 + r;
                out[(size_t)row * DIM + col] = acc[mi][ni][r] + bias;
            }
    }
}

// ---------------------------------------------------------------------------
// Fused sub-state + chunk-state partial. Grid (64 chunks, 4 subs, 2 g).
//   H[j] local recurrence end-state -> S ; R[j] = sum B*x*a -> R ; dprod (g==0)
// ---------------------------------------------------------------------------
__global__ __launch_bounds__(192)
void state_kernel(const float* __restrict__ proj,
                  const float* __restrict__ Abar,
                  const float* __restrict__ Bm,      // stride 128
                  float* __restrict__ S,
                  float* __restrict__ R,
                  float* __restrict__ dprod)
{
    int bc = blockIdx.x, s = blockIdx.y, g = blockIdx.z;
    int dd = threadIdx.x;
    int t0 = bc * PCHUNK + s * SUB;
    __shared__ float Bs[SUB][NPG2];
    for (int idx = threadIdx.x; idx < SUB * NPG2; idx += 192) {
        int i = idx >> 5, j = idx & 31;
        Bs[i][j] = Bm[(size_t)(t0 + i) * 128 + g * NPG2 + j];
    }
    __syncthreads();
    float H[NPG2] = {}, Rr[NPG2] = {};
    float cp = 1.f;
    float a_cur = fabsf(Abar[(size_t)t0 * DIM + dd]) + 1e-8f;
    float x_cur = proj[(size_t)t0 * 384 + dd];
    for (int i = 0; i < SUB; ++i) {
        float a_nxt = 0.f, x_nxt = 0.f;
        if (i + 1 < SUB) {
            a_nxt = fabsf(Abar[(size_t)(t0 + i + 1) * DIM + dd]) + 1e-8f;
            x_nxt = proj[(size_t)(t0 + i + 1) * 384 + dd];
        }
        cp *= a_cur;
        #pragma unroll
        for (int j = 0; j < NPG2; ++j) {
            float u = Bs[i][j] * x_cur;
            H[j]  = fmaf(a_cur, H[j], u);
            Rr[j] = fmaf(u, a_cur, Rr[j]);
        }
        a_cur = a_nxt; x_cur = x_nxt;
    }
    size_t base = (((size_t)(bc * NSUB + s)) * NST + g * NPG2) * DIM + dd;
    #pragma unroll
    for (int j = 0; j < NPG2; ++j) {
        S[base + (size_t)j * DIM] = H[j];
        R[base + (size_t)j * DIM] = Rr[j];
    }
    if (g == 0) dprod[(size_t)(bc * NSUB + s) * DIM + dd] = cp;
}

// ---------------------------------------------------------------------------
// Inter-chunk scan (prev only). Threads over (b, nn, dd/4) = 12288.
// ---------------------------------------------------------------------------
__global__ __launch_bounds__(256)
void scan_kernel(const float* __restrict__ dprod,
                 const float* __restrict__ R,
                 float* __restrict__ prev)
{
    int v = blockIdx.x * 256 + threadIdx.x;
    if (v >= BATCH * NST * 48) return;
    int dd = (v % 48) * 4;
    int nn = (v / 48) % NST;
    int b  = v / (48 * NST);
    const size_t Q2 = (size_t)NST * DIM;
    float4 st = {0.f, 0.f, 0.f, 0.f};
    for (int c = 0; c < CPB; ++c) {
        int bc = b * CPB + c;
        size_t so = ((size_t)(bc * NSUB) * NST + nn) * DIM + dd;
        float4 Rs = {0.f, 0.f, 0.f, 0.f};
        float4 cA = {1.f, 1.f, 1.f, 1.f};
        #pragma unroll
        for (int s = 0; s < NSUB; ++s) {
            float4 dp = *(const float4*)(dprod + (size_t)(bc * NSUB + s) * DIM + dd);
            float4 Rv = *(const float4*)(R + so + (size_t)s * Q2);
            cA.x *= dp.x; cA.y *= dp.y; cA.z *= dp.z; cA.w *= dp.w;
            Rs.x += Rv.x; Rs.y += Rv.y; Rs.z += Rv.z; Rs.w += Rv.w;
        }
        size_t po = ((size_t)bc * NST + nn) * DIM + dd;
        *(float4*)(prev + po) = st;
        st.x = fmaf(st.x, cA.x, Rs.x);
        st.y = fmaf(st.y, cA.y, Rs.y);
        st.z = fmaf(st.z, cA.z, Rs.z);
        st.w = fmaf(st.w, cA.w, Rs.w);
    }
}

// ---------------------------------------------------------------------------
// Intra recurrence. H initialized to the sub-chunk carry (computed inline from
// S + dprod), so H itself carries cp*CI; y = sum_j C*(H+P). Grid (64,4,2).
// ---------------------------------------------------------------------------
__global__ __launch_bounds__(192)
void intra_kernel(const float* __restrict__ proj,
                  const float* __restrict__ Abar,
                  const float* __restrict__ Bm,     // stride 128
                  const float* __restrict__ Cm,     // stride 128 (offset +64)
                  const float* __restrict__ prev,
                  const float* __restrict__ S,
                  const float* __restrict__ dprod,
                  float* __restrict__ p_y)
{
    int bc = blockIdx.x, s = blockIdx.y, g = blockIdx.z;
    int dd = threadIdx.x;
    int t0 = bc * PCHUNK + s * SUB;
    __shared__ float Bs[SUB][NPG2];
    __shared__ float Cs[SUB][NPG2];
    for (int idx = threadIdx.x; idx < SUB * NPG2; idx += 192) {
        int i = idx >> 5, j = idx & 31;
        Bs[i][j] = Bm[(size_t)(t0 + i) * 128 + g * NPG2 + j];
        Cs[i][j] = Cm[(size_t)(t0 + i) * 128 + g * NPG2 + j];
    }
    // carry-in: H = scan over preceding sub-chunks of this chunk
    float H[NPG2] = {}, P[NPG2];
    for (int k = 0; k < s; ++k) {
        float dpk = dprod[(size_t)(bc * NSUB + k) * DIM + dd];
        size_t sb = (((size_t)(bc * NSUB + k)) * NST + g * NPG2) * DIM + dd;
        #pragma unroll
        for (int j = 0; j < NPG2; ++j)
            H[j] = fmaf(H[j], dpk, S[sb + (size_t)j * DIM]);
    }
    #pragma unroll
    for (int j = 0; j < NPG2; ++j)
        P[j] = prev[((size_t)bc * NST + g * NPG2 + j) * DIM + dd];
    __syncthreads();

    float a_cur = fabsf(Abar[(size_t)t0 * DIM + dd]) + 1e-8f;
    float x_cur = proj[(size_t)t0 * 384 + dd];
    for (int i = 0; i < SUB; ++i) {
        int t = t0 + i;
        float a_nxt = 0.f, x_nxt = 0.f;
        if (i + 1 < SUB) {
            a_nxt = fabsf(Abar[(size_t)(t + 1) * DIM + dd]) + 1e-8f;
            x_nxt = proj[(size_t)(t + 1) * 384 + dd];
        }
        float ya[4] = {0.f, 0.f, 0.f, 0.f};
        #pragma unroll
        for (int j = 0; j < NPG2; ++j) {
            float u = Bs[i][j] * x_cur;
            H[j] = fmaf(a_cur, H[j], u);
            ya[j & 3] = fmaf(Cs[i][j], H[j] + P[j], ya[j & 3]);
        }
        p_y[((size_t)g * TOK + t) * DIM + dd] = (ya[0] + ya[1]) + (ya[2] + ya[3]);
        a_cur = a_nxt; x_cur = x_nxt;
    }
}

// y_g = (p_y0 + p_y1) * silu(z)  -> bf16
__global__ __launch_bounds__(256)
void gate_kernel(const float* __restrict__ p_y,
                 const float* __restrict__ proj,
                 unsigned short* __restrict__ ygb)
{
    int v = blockIdx.x * 256 + threadIdx.x;
    if (v >= TOK * 48) return;
    int t = v / 48;
    int dd = (v % 48) * 4;
    const size_t Q = (size_t)TOK * DIM;
    size_t off = (size_t)t * DIM + dd;
    float4 y0 = *(const float4*)(p_y + off);
    float4 y1 = *(const float4*)(p_y + off + Q);
    float4 z  = *(const float4*)(proj + (size_t)t * 384 + DIM + dd);
    ushort4 r;
    r.x = f2bf((y0.x+y1.x) * (z.x / (1.f + expf(-z.x))));
    r.y = f2bf((y0.y+y1.y) * (z.y / (1.f + expf(-z.y))));
    r.z = f2bf((y0.z+y1.z) * (z.z / (1.f + expf(-z.z))));
    r.w = f2bf((y0.w+y1.w) * (z.w / (1.f + expf(-z.w))));
    *(ushort4*)(ygb + off) = r;
}

// ---------------------------------------------------------------------------
extern "C" void kernel_launch(void* const* d_in, const int* in_sizes, int n_in,
                              void* d_out, int out_size, void* d_ws, size_t ws_size,
                              hipStream_t stream)
{
    (void)in_sizes; (void)n_in; (void)out_size; (void)ws_size;
    const float* x     = (const float*)d_in[0];
    const float* A_log = (const float*)d_in[1];
    const float* W_B   = (const float*)d_in[2];
    const float* W_C   = (const float*)d_in[3];
    const float* W_dt  = (const float*)d_in[4];
    const float* b_dt  = (const float*)d_in[5];
    const float* W_xp  = (const float*)d_in[6];
    const float* b_xp  = (const float*)d_in[7];
    const float* W_out = (const float*)d_in[8];
    const float* b_out = (const float*)d_in[9];
    float* out = (float*)d_out;

    char* w = (char*)d_ws;
    auto take = [&](size_t bytes) { char* p = w; w += (bytes + 255) & ~(size_t)255; return p; };
    float*          proj   = (float*)         take((size_t)TOK*384*4);
    unsigned short* projb  = (unsigned short*)take((size_t)TOK*384*2);
    unsigned short* xb     = (unsigned short*)take((size_t)TOK*DIM*2);
    unsigned short* wxpb   = (unsigned short*)take((size_t)384*DIM*2);
    unsigned short* wbcdtb = (unsigned short*)take((size_t)320*DIM*2);
    unsigned short* woutb  = (unsigned short*)take((size_t)DIM*DIM*2);
    float*          BC     = (float*)         take((size_t)TOK*128*4);
    float*          Abar   = (float*)         take((size_t)TOK*DIM*4);
    float*          dprod  = (float*)         take((size_t)NCHUNKS*NSUB*DIM*4);
    float*          prev   = (float*)         take((size_t)NCHUNKS*NST*DIM*4);
    float*          Sarr   = (float*)         take((size_t)NCHUNKS*NSUB*NST*DIM*4);
    float*          Rarr   = (float*)         take((size_t)NCHUNKS*NSUB*NST*DIM*4);
    float*          p_y    = (float*)         take((size_t)NG2*TOK*DIM*4);
    unsigned short* ygb    = (unsigned short*)take((size_t)TOK*DIM*2);
    const float* Bm = BC;         // stride 128
    const float* Cm = BC + 64;    // stride 128

    dim3 blk(256);

    cast_kernel<<<dim3((436224 + 255)/256), blk, 0, stream>>>(
        x, W_xp, W_B, W_C, W_dt, W_out, xb, wxpb, wbcdtb, woutb);
    proj_gemm<<<dim3(TOK/256, 384/64), blk, 0, stream>>>(xb, wxpb, b_xp, proj, projb);
    bcdt_gemm<<<dim3(TOK/256, 320/64), blk, 0, stream>>>(projb, wbcdtb, b_dt, A_log, BC, Abar);
    state_kernel<<<dim3(NCHUNKS, NSUB, NG2), dim3(192), 0, stream>>>(
        proj, Abar, Bm, Sarr, Rarr, dprod);
    scan_kernel<<<dim3((BATCH*NST*48 + 255)/256), blk, 0, stream>>>(dprod, Rarr, prev);
    intra_kernel<<<dim3(NCHUNKS, NSUB, NG2), dim3(192), 0, stream>>>(
        proj, Abar, Bm, Cm, prev, Sarr, dprod, p_y);
    gate_kernel<<<dim3((TOK*48 + 255)/256), blk, 0, stream>>>(p_y, proj, ygb);
    out_gemm<<<dim3(TOK/256, DIM/64), blk, 0, stream>>>(ygb, woutb, b_out, out);
}

// Round 5
// 179.165 us; speedup vs baseline: 1.4989x; 1.0507x over previous
//
#include <hip/hip_runtime.h>
#include <math.h>

// Problem constants: B=4, L=2048, d=192, n=64, chunk=128
#define TOK      8192
#define DIM      192
#define NST      64
#define PCHUNK   128
#define NCHUNKS  64
#define CPB      16
#define BATCH    4
#define SUB      32
#define NSUB     4
#define NG       4      // n-groups
#define NPG      16     // n per group

typedef __attribute__((ext_vector_type(8))) short  bf16x8;
typedef __attribute__((ext_vector_type(4))) float  f32x4;

__device__ __forceinline__ unsigned short f2bf(float f) {
    unsigned int u = __float_as_uint(f);
    u += 0x7fff + ((u >> 16) & 1);          // RNE
    return (unsigned short)(u >> 16);
}
__device__ __forceinline__ float bf2f(unsigned short h) {
    return __uint_as_float(((unsigned int)h) << 16);
}

// ---------------------------------------------------------------------------
// Cast x + weights to bf16.  wbcdtb rows: [W_B(64)|W_C(64)|W_dt(192)] x 192
// ---------------------------------------------------------------------------
__global__ __launch_bounds__(256)
void cast_kernel(const float* __restrict__ x,   const float* __restrict__ Wxp,
                 const float* __restrict__ WB,  const float* __restrict__ WC,
                 const float* __restrict__ Wdt, const float* __restrict__ Wout,
                 unsigned short* __restrict__ xb,     unsigned short* __restrict__ wxpb,
                 unsigned short* __restrict__ wbcdtb, unsigned short* __restrict__ woutb)
{
    int u = blockIdx.x * 256 + threadIdx.x;
    const float* src; unsigned short* dst; int idx;
    if      (u < 393216) { src = x;    dst = xb;             idx = u; }
    else if (u < 411648) { src = Wxp;  dst = wxpb;           idx = u - 393216; }
    else if (u < 414720) { src = WB;   dst = wbcdtb;         idx = u - 411648; }
    else if (u < 417792) { src = WC;   dst = wbcdtb + 12288; idx = u - 414720; }
    else if (u < 427008) { src = Wdt;  dst = wbcdtb + 24576; idx = u - 417792; }
    else if (u < 436224) { src = Wout; dst = woutb;          idx = u - 427008; }
    else return;
    float4 v = *(const float4*)(src + (size_t)idx * 4);
    ushort4 r; r.x = f2bf(v.x); r.y = f2bf(v.y); r.z = f2bf(v.z); r.w = f2bf(v.w);
    *(ushort4*)(dst + (size_t)idx * 4) = r;
}

// ---------------------------------------------------------------------------
// MFMA wave-tile: 64x64 of X[M,K] @ W[N,K]^T (bf16 -> fp32)
// ---------------------------------------------------------------------------
__device__ __forceinline__
void mfma_64x64(const unsigned short* __restrict__ X, int ldx,
                const unsigned short* __restrict__ W, int K,
                int m_wave, int n0, int lr, int kg, f32x4 acc[4][4])
{
    for (int k0 = 0; k0 < K; k0 += 32) {
        bf16x8 af[4], bfr[4];
        #pragma unroll
        for (int mi = 0; mi < 4; ++mi)
            af[mi] = *(const bf16x8*)(X + (size_t)(m_wave + mi*16 + lr) * ldx + k0 + kg*8);
        #pragma unroll
        for (int ni = 0; ni < 4; ++ni)
            bfr[ni] = *(const bf16x8*)(W + (size_t)(n0 + ni*16 + lr) * K + k0 + kg*8);
        #pragma unroll
        for (int mi = 0; mi < 4; ++mi)
            #pragma unroll
            for (int ni = 0; ni < 4; ++ni)
                acc[mi][ni] = __builtin_amdgcn_mfma_f32_16x16x32_bf16(
                                  af[mi], bfr[ni], acc[mi][ni], 0, 0, 0);
    }
}

__global__ __launch_bounds__(256)
void proj_gemm(const unsigned short* __restrict__ xb,
               const unsigned short* __restrict__ wxpb,
               const float* __restrict__ b_xp,
               float* __restrict__ proj, unsigned short* __restrict__ projb)
{
    const int lane = threadIdx.x & 63, wave = threadIdx.x >> 6;
    const int m_wave = blockIdx.x * 256 + wave * 64;
    const int n0 = blockIdx.y * 64;
    const int lr = lane & 15, kg = lane >> 4;
    f32x4 acc[4][4] = {};
    mfma_64x64(xb, DIM, wxpb, DIM, m_wave, n0, lr, kg, acc);
    #pragma unroll
    for (int ni = 0; ni < 4; ++ni) {
        int col = n0 + ni*16 + lr;
        float bias = b_xp[col];
        #pragma unroll
        for (int mi = 0; mi < 4; ++mi)
            #pragma unroll
            for (int r = 0; r < 4; ++r) {
                int row = m_wave + mi*16 + kg*4 + r;
                float v = acc[mi][ni][r] + bias;
                proj [(size_t)row * 384 + col] = v;
                projb[(size_t)row * 384 + col] = f2bf(v);
            }
    }
}

__global__ __launch_bounds__(256)
void bcdt_gemm(const unsigned short* __restrict__ projb,
               const unsigned short* __restrict__ wbcdtb,
               const float* __restrict__ b_dt, const float* __restrict__ A_log,
               float* __restrict__ BC, float* __restrict__ Abar)
{
    const int lane = threadIdx.x & 63, wave = threadIdx.x >> 6;
    const int m_wave = blockIdx.x * 256 + wave * 64;
    const int n0 = blockIdx.y * 64;
    const int lr = lane & 15, kg = lane >> 4;
    f32x4 acc[4][4] = {};
    mfma_64x64(projb, 384, wbcdtb, DIM, m_wave, n0, lr, kg, acc);
    if (n0 < 128) {
        #pragma unroll
        for (int ni = 0; ni < 4; ++ni) {
            int col = n0 + ni*16 + lr;
            #pragma unroll
            for (int mi = 0; mi < 4; ++mi)
                #pragma unroll
                for (int r = 0; r < 4; ++r) {
                    int row = m_wave + mi*16 + kg*4 + r;
                    BC[(size_t)row * 128 + col] = acc[mi][ni][r];
                }
        }
    } else {
        #pragma unroll
        for (int ni = 0; ni < 4; ++ni) {
            int c2 = n0 - 128 + ni*16 + lr;
            float bias = b_dt[c2];
            float Av = -expf(A_log[c2]);
            #pragma unroll
            for (int mi = 0; mi < 4; ++mi)
                #pragma unroll
                for (int r = 0; r < 4; ++r) {
                    int row = m_wave + mi*16 + kg*4 + r;
                    float v = acc[mi][ni][r] + bias;
                    float sp = (v > 20.f) ? v : log1pf(expf(v));
                    Abar[(size_t)row * DIM + c2] = expf(sp * Av);
                }
        }
    }
}

__global__ __launch_bounds__(256)
void out_gemm(const unsigned short* __restrict__ ygb,
              const unsigned short* __restrict__ woutb,
              const float* __restrict__ b_out, float* __restrict__ out)
{
    const int lane = threadIdx.x & 63, wave = threadIdx.x >> 6;
    const int m_wave = blockIdx.x * 256 + wave * 64;
    const int n0 = blockIdx.y * 64;
    const int lr = lane & 15, kg = lane >> 4;
    f32x4 acc[4][4] = {};
    mfma_64x64(ygb, DIM, woutb, DIM, m_wave, n0, lr, kg, acc);
    #pragma unroll
    for (int ni = 0; ni < 4; ++ni) {
        int col = n0 + ni*16 + lr;
        float bias = b_out[col];
        #pragma unroll
        for (int mi = 0; mi < 4; ++mi)
            #pragma unroll
            for (int r = 0; r < 4; ++r) {
                int row = m_wave + mi*16 + kg*4 + r;
                out[(size_t)row * DIM + col] = acc[mi][ni][r] + bias;
            }
    }
}

// ---------------------------------------------------------------------------
// Fused sub-state + chunk-state partial. Grid (64, 4 subs, 4 g), 192 thr.
// ---------------------------------------------------------------------------
__global__ __launch_bounds__(192)
void state_kernel(const float* __restrict__ proj,
                  const float* __restrict__ Abar,
                  const float* __restrict__ Bm,      // stride 128
                  float* __restrict__ S,
                  float* __restrict__ R,
                  float* __restrict__ dprod)
{
    int bc = blockIdx.x, s = blockIdx.y, g = blockIdx.z;
    int dd = threadIdx.x;
    int t0 = bc * PCHUNK + s * SUB;
    __shared__ float Bs[SUB][NPG];
    if (threadIdx.x < SUB * NPG / 4) {
        int row = threadIdx.x >> 2, c4 = threadIdx.x & 3;
        *(float4*)&Bs[row][c4 * 4] =
            *(const float4*)(Bm + (size_t)(t0 + row) * 128 + g * NPG + c4 * 4);
    }
    __syncthreads();
    float H[NPG] = {}, Rr[NPG] = {};
    float cp = 1.f;
    float a_cur = fabsf(Abar[(size_t)t0 * DIM + dd]) + 1e-8f;
    float x_cur = proj[(size_t)t0 * 384 + dd];
    for (int i = 0; i < SUB; ++i) {
        float a_nxt = 0.f, x_nxt = 0.f;
        if (i + 1 < SUB) {
            a_nxt = fabsf(Abar[(size_t)(t0 + i + 1) * DIM + dd]) + 1e-8f;
            x_nxt = proj[(size_t)(t0 + i + 1) * 384 + dd];
        }
        cp *= a_cur;
        float4 b0 = *(const float4*)&Bs[i][0];
        float4 b1 = *(const float4*)&Bs[i][4];
        float4 b2 = *(const float4*)&Bs[i][8];
        float4 b3 = *(const float4*)&Bs[i][12];
        float bb[NPG] = {b0.x,b0.y,b0.z,b0.w, b1.x,b1.y,b1.z,b1.w,
                         b2.x,b2.y,b2.z,b2.w, b3.x,b3.y,b3.z,b3.w};
        #pragma unroll
        for (int j = 0; j < NPG; ++j) {
            float u = bb[j] * x_cur;
            H[j]  = fmaf(a_cur, H[j], u);
            Rr[j] = fmaf(u, a_cur, Rr[j]);
        }
        a_cur = a_nxt; x_cur = x_nxt;
    }
    size_t base = (((size_t)(bc * NSUB + s)) * NST + g * NPG) * DIM + dd;
    #pragma unroll
    for (int j = 0; j < NPG; ++j) {
        S[base + (size_t)j * DIM] = H[j];
        R[base + (size_t)j * DIM] = Rr[j];
    }
    if (g == 0) dprod[(size_t)(bc * NSUB + s) * DIM + dd] = cp;
}

// ---------------------------------------------------------------------------
// Per-chunk reductions: cA[bc,dd] = prod_s dprod ; Rsum[bc,nn,dd] = sum_s R
// float4 units.
// ---------------------------------------------------------------------------
__global__ __launch_bounds__(256)
void reduce_kernel(const float* __restrict__ dprod,
                   const float* __restrict__ R,
                   float* __restrict__ cA,
                   float* __restrict__ Rsum)
{
    int u = blockIdx.x * 256 + threadIdx.x;
    const int NR = NCHUNKS * NST * 48;          // Rsum units
    if (u < NR) {
        int dd = (u % 48) * 4;
        int nn = (u / 48) % NST;
        int bc = u / (48 * NST);
        const size_t Q2 = (size_t)NST * DIM;
        size_t so = ((size_t)(bc * NSUB) * NST + nn) * DIM + dd;
        float4 acc = {0.f, 0.f, 0.f, 0.f};
        #pragma unroll
        for (int s = 0; s < NSUB; ++s) {
            float4 v = *(const float4*)(R + so + (size_t)s * Q2);
            acc.x += v.x; acc.y += v.y; acc.z += v.z; acc.w += v.w;
        }
        *(float4*)(Rsum + ((size_t)bc * NST + nn) * DIM + dd) = acc;
    } else if (u < NR + NCHUNKS * 48) {
        int v = u - NR;
        int dd = (v % 48) * 4;
        int bc = v / 48;
        float4 acc = {1.f, 1.f, 1.f, 1.f};
        #pragma unroll
        for (int s = 0; s < NSUB; ++s) {
            float4 dp = *(const float4*)(dprod + (size_t)(bc * NSUB + s) * DIM + dd);
            acc.x *= dp.x; acc.y *= dp.y; acc.z *= dp.z; acc.w *= dp.w;
        }
        *(float4*)(cA + (size_t)bc * DIM + dd) = acc;
    }
}

// ---------------------------------------------------------------------------
// Inter-chunk scan: 16 steps, 2 float4 loads/step (prefetched)
// ---------------------------------------------------------------------------
__global__ __launch_bounds__(256)
void scan_kernel(const float* __restrict__ cA,
                 const float* __restrict__ Rsum,
                 float* __restrict__ prev)
{
    int v = blockIdx.x * 256 + threadIdx.x;
    if (v >= BATCH * NST * 48) return;
    int dd = (v % 48) * 4;
    int nn = (v / 48) % NST;
    int b  = v / (48 * NST);
    int bc0 = b * CPB;
    float4 st = {0.f, 0.f, 0.f, 0.f};
    float4 a_cur = *(const float4*)(cA + (size_t)bc0 * DIM + dd);
    float4 r_cur = *(const float4*)(Rsum + ((size_t)bc0 * NST + nn) * DIM + dd);
    for (int c = 0; c < CPB; ++c) {
        int bc = bc0 + c;
        float4 a_nxt = {0,0,0,0}, r_nxt = {0,0,0,0};
        if (c + 1 < CPB) {
            a_nxt = *(const float4*)(cA + (size_t)(bc + 1) * DIM + dd);
            r_nxt = *(const float4*)(Rsum + ((size_t)(bc + 1) * NST + nn) * DIM + dd);
        }
        *(float4*)(prev + ((size_t)bc * NST + nn) * DIM + dd) = st;
        st.x = fmaf(st.x, a_cur.x, r_cur.x);
        st.y = fmaf(st.y, a_cur.y, r_cur.y);
        st.z = fmaf(st.z, a_cur.z, r_cur.z);
        st.w = fmaf(st.w, a_cur.w, r_cur.w);
        a_cur = a_nxt; r_cur = r_nxt;
    }
}

// ---------------------------------------------------------------------------
// Intra recurrence. H seeded with inline carry scan over earlier sub-chunks.
// Grid (64, 4 subs, 4 g), 192 thr. p_y written bf16.
// ---------------------------------------------------------------------------
__global__ __launch_bounds__(192)
void intra_kernel(const float* __restrict__ proj,
                  const float* __restrict__ Abar,
                  const float* __restrict__ Bm,     // stride 128
                  const float* __restrict__ Cm,     // stride 128 (offset +64)
                  const float* __restrict__ prev,
                  const float* __restrict__ S,
                  const float* __restrict__ dprod,
                  unsigned short* __restrict__ p_y)
{
    int bc = blockIdx.x, s = blockIdx.y, g = blockIdx.z;
    int dd = threadIdx.x;
    int t0 = bc * PCHUNK + s * SUB;
    __shared__ float Bs[SUB][NPG];
    __shared__ float Cs[SUB][NPG];
    if (threadIdx.x < SUB * NPG / 2) {          // 256 float4 loads, have 192 thr
        // first 128 threads: Bs ; next 64 handled below in second pass
    }
    {
        int nunits = SUB * NPG / 4;             // 128 per matrix
        for (int idx = threadIdx.x; idx < 2 * nunits; idx += 192) {
            int m = idx >= nunits;
            int q = idx - m * nunits;
            int row = q >> 2, c4 = q & 3;
            const float* src = (m ? Cm : Bm) + (size_t)(t0 + row) * 128
                             + (m ? 64 : 0) + g * NPG + c4 * 4;
            float4 v = *(const float4*)src;
            if (m) *(float4*)&Cs[row][c4 * 4] = v;
            else   *(float4*)&Bs[row][c4 * 4] = v;
        }
    }
    float H[NPG] = {}, P[NPG];
    for (int k = 0; k < s; ++k) {
        float dpk = dprod[(size_t)(bc * NSUB + k) * DIM + dd];
        size_t sb = (((size_t)(bc * NSUB + k)) * NST + g * NPG) * DIM + dd;
        #pragma unroll
        for (int j = 0; j < NPG; ++j)
            H[j] = fmaf(H[j], dpk, S[sb + (size_t)j * DIM]);
    }
    #pragma unroll
    for (int j = 0; j < NPG; ++j)
        P[j] = prev[((size_t)bc * NST + g * NPG + j) * DIM + dd];
    __syncthreads();

    float a_cur = fabsf(Abar[(size_t)t0 * DIM + dd]) + 1e-8f;
    float x_cur = proj[(size_t)t0 * 384 + dd];
    for (int i = 0; i < SUB; ++i) {
        int t = t0 + i;
        float a_nxt = 0.f, x_nxt = 0.f;
        if (i + 1 < SUB) {
            a_nxt = fabsf(Abar[(size_t)(t + 1) * DIM + dd]) + 1e-8f;
            x_nxt = proj[(size_t)(t + 1) * 384 + dd];
        }
        float4 b0 = *(const float4*)&Bs[i][0];
        float4 b1 = *(const float4*)&Bs[i][4];
        float4 b2 = *(const float4*)&Bs[i][8];
        float4 b3 = *(const float4*)&Bs[i][12];
        float4 c0 = *(const float4*)&Cs[i][0];
        float4 c1 = *(const float4*)&Cs[i][4];
        float4 c2 = *(const float4*)&Cs[i][8];
        float4 c3 = *(const float4*)&Cs[i][12];
        float bb[NPG] = {b0.x,b0.y,b0.z,b0.w, b1.x,b1.y,b1.z,b1.w,
                         b2.x,b2.y,b2.z,b2.w, b3.x,b3.y,b3.z,b3.w};
        float cc[NPG] = {c0.x,c0.y,c0.z,c0.w, c1.x,c1.y,c1.z,c1.w,
                         c2.x,c2.y,c2.z,c2.w, c3.x,c3.y,c3.z,c3.w};
        float ya[4] = {0.f, 0.f, 0.f, 0.f};
        #pragma unroll
        for (int j = 0; j < NPG; ++j) {
            H[j] = fmaf(a_cur, H[j], bb[j] * x_cur);
            ya[j & 3] = fmaf(cc[j], H[j] + P[j], ya[j & 3]);
        }
        p_y[((size_t)g * TOK + t) * DIM + dd] = f2bf((ya[0] + ya[1]) + (ya[2] + ya[3]));
        a_cur = a_nxt; x_cur = x_nxt;
    }
}

// y_g = (sum of 4 bf16 partials) * silu(z)  -> bf16
__global__ __launch_bounds__(256)
void gate_kernel(const unsigned short* __restrict__ p_y,
                 const float* __restrict__ proj,
                 unsigned short* __restrict__ ygb)
{
    int v = blockIdx.x * 256 + threadIdx.x;
    if (v >= TOK * 48) return;
    int t = v / 48;
    int dd = (v % 48) * 4;
    const size_t Q = (size_t)TOK * DIM;
    size_t off = (size_t)t * DIM + dd;
    float acc[4] = {0.f, 0.f, 0.f, 0.f};
    #pragma unroll
    for (int gidx = 0; gidx < NG; ++gidx) {
        ushort4 y = *(const ushort4*)(p_y + off + (size_t)gidx * Q);
        acc[0] += bf2f(y.x); acc[1] += bf2f(y.y);
        acc[2] += bf2f(y.z); acc[3] += bf2f(y.w);
    }
    float4 z = *(const float4*)(proj + (size_t)t * 384 + DIM + dd);
    ushort4 r;
    r.x = f2bf(acc[0] * (z.x / (1.f + expf(-z.x))));
    r.y = f2bf(acc[1] * (z.y / (1.f + expf(-z.y))));
    r.z = f2bf(acc[2] * (z.z / (1.f + expf(-z.z))));
    r.w = f2bf(acc[3] * (z.w / (1.f + expf(-z.w))));
    *(ushort4*)(ygb + off) = r;
}

// ---------------------------------------------------------------------------
extern "C" void kernel_launch(void* const* d_in, const int* in_sizes, int n_in,
                              void* d_out, int out_size, void* d_ws, size_t ws_size,
                              hipStream_t stream)
{
    (void)in_sizes; (void)n_in; (void)out_size; (void)ws_size;
    const float* x     = (const float*)d_in[0];
    const float* A_log = (const float*)d_in[1];
    const float* W_B   = (const float*)d_in[2];
    const float* W_C   = (const float*)d_in[3];
    const float* W_dt  = (const float*)d_in[4];
    const float* b_dt  = (const float*)d_in[5];
    const float* W_xp  = (const float*)d_in[6];
    const float* b_xp  = (const float*)d_in[7];
    const float* W_out = (const float*)d_in[8];
    const float* b_out = (const float*)d_in[9];
    float* out = (float*)d_out;

    char* w = (char*)d_ws;
    auto take = [&](size_t bytes) { char* p = w; w += (bytes + 255) & ~(size_t)255; return p; };
    float*          proj   = (float*)         take((size_t)TOK*384*4);
    unsigned short* projb  = (unsigned short*)take((size_t)TOK*384*2);
    unsigned short* xb     = (unsigned short*)take((size_t)TOK*DIM*2);
    unsigned short* wxpb   = (unsigned short*)take((size_t)384*DIM*2);
    unsigned short* wbcdtb = (unsigned short*)take((size_t)320*DIM*2);
    unsigned short* woutb  = (unsigned short*)take((size_t)DIM*DIM*2);
    float*          BC     = (float*)         take((size_t)TOK*128*4);
    float*          Abar   = (float*)         take((size_t)TOK*DIM*4);
    float*          dprod  = (float*)         take((size_t)NCHUNKS*NSUB*DIM*4);
    float*          cAc    = (float*)         take((size_t)NCHUNKS*DIM*4);
    float*          prev   = (float*)         take((size_t)NCHUNKS*NST*DIM*4);
    float*          Rsum   = (float*)         take((size_t)NCHUNKS*NST*DIM*4);
    float*          Sarr   = (float*)         take((size_t)NCHUNKS*NSUB*NST*DIM*4);
    float*          Rarr   = (float*)         take((size_t)NCHUNKS*NSUB*NST*DIM*4);
    unsigned short* p_y    = (unsigned short*)take((size_t)NG*TOK*DIM*2);
    unsigned short* ygb    = (unsigned short*)take((size_t)TOK*DIM*2);
    const float* Bm = BC;         // stride 128
    const float* Cm = BC;         // +64 handled inside intra staging
    dim3 blk(256);

    cast_kernel<<<dim3((436224 + 255)/256), blk, 0, stream>>>(
        x, W_xp, W_B, W_C, W_dt, W_out, xb, wxpb, wbcdtb, woutb);
    proj_gemm<<<dim3(TOK/256, 384/64), blk, 0, stream>>>(xb, wxpb, b_xp, proj, projb);
    bcdt_gemm<<<dim3(TOK/256, 320/64), blk, 0, stream>>>(projb, wbcdtb, b_dt, A_log, BC, Abar);
    state_kernel<<<dim3(NCHUNKS, NSUB, NG), dim3(192), 0, stream>>>(
        proj, Abar, Bm, Sarr, Rarr, dprod);
    reduce_kernel<<<dim3((NCHUNKS*NST*48 + NCHUNKS*48 + 255)/256), blk, 0, stream>>>(
        dprod, Rarr, cAc, Rsum);
    scan_kernel<<<dim3((BATCH*NST*48 + 255)/256), blk, 0, stream>>>(cAc, Rsum, prev);
    intra_kernel<<<dim3(NCHUNKS, NSUB, NG), dim3(192), 0, stream>>>(
        proj, Abar, Bm, Cm, prev, Sarr, dprod, p_y);
    gate_kernel<<<dim3((TOK*48 + 255)/256), blk, 0, stream>>>(p_y, proj, ygb);
    out_gemm<<<dim3(TOK/256, DIM/64), blk, 0, stream>>>(ygb, woutb, b_out, out);
}